// Round 5
// baseline (42535.941 us; speedup 1.0000x reference)
//
#include <hip/hip_runtime.h>
#include <hip/hip_cooperative_groups.h>

namespace cg = cooperative_groups;

#define NB 36
#define NT 60
#define NTHR 256
#define WLSZ 4896   // floats: max(conv 64cin*9*8co=4608, fc1 32*68+40*68=4896)

struct Params {
  const float *data;
  const float *W0, *b0, *W1, *b1, *W2, *b2, *Wf1, *bf1, *Wf2, *bf2;
  float *xb, *w0t, *w1t, *w2t;
  float *out0, *outp1, *outp2, *u1s;
  float *dm0, *dm1, *dmp1, *dm2, *dmp2, *dmh1, *dmh2;
  float *acc;
  float *dmz; int dmz_n4;
  unsigned int *tk;
};

// ---- shared prep work (grid-stride) ----
__device__ __forceinline__ void prep_all(const Params& p, int gt, int STR){
  if(gt < NB*11) p.acc[gt] = 0.f;
  for(int i=gt; i<p.dmz_n4; i+=STR) ((float4*)p.dmz)[i] = make_float4(0.f,0.f,0.f,0.f);
  for(int i=gt; i<NT*NB*2*32*32; i+=STR){
    int t = i / (NB*2*32*32);
    int r = i % (NB*2*32*32);
    p.xb[i] = (p.data[(size_t)r*NT + t] > 1.0f) ? 1.0f : 0.0f;
  }
  for(int i=gt; i<2*9*64; i+=STR){
    int co=i%64, rr=i/64; p.w0t[i] = p.W0[(co*2 + rr/9)*9 + rr%9];
  }
  for(int i=gt; i<64*9*128; i+=STR){
    int co=i%128, rr=i/128; p.w1t[i] = p.W1[(co*64 + rr/9)*9 + rr%9];
  }
  for(int i=gt; i<128*9*128; i+=STR){
    int co=i%128, rr=i/128; p.w2t[i] = p.W2[(co*128 + rr/9)*9 + rr%9];
  }
}

// ---- fused conv3x3 + LIAF (+ optional avgpool2 + LIAF), one tile ----
// Thread: w = tid%HW, ty = tid/HW; PX rows x CO couts. Weights staged in LDS
// in CS-cin chunks (CS=Cin -> single stage).
template<int Cin,int Cout,int HW,int CO,int PX,int TY,bool POOL,int CS>
__device__ __forceinline__
void conv_tile(int tile, int tid, const float* __restrict__ x,
               const float* __restrict__ wt, const float* __restrict__ bias,
               float* __restrict__ dm, float* __restrict__ out,
               float* __restrict__ dmp, float* __restrict__ outp,
               float* __restrict__ wl)
{
  const int NCOG = Cout/CO;
  const int TH   = PX*TY;
  const int NHG  = HW/TH;
  const int NH4  = CO/4;
  int cog = tile % NCOG;
  int hg  = (tile/NCOG) % NHG;
  int b   = tile/(NCOG*NHG);
  int w   = tid % HW;
  int ty  = tid / HW;
  int h0  = hg*TH + ty*PX;

  float accs[PX][CO];
  #pragma unroll
  for(int p=0;p<PX;p++)
    #pragma unroll
    for(int c=0;c<CO;c++) accs[p][c]=0.f;

  for(int cs=0; cs<Cin; cs+=CS){
    __syncthreads();                       // protect prior wl readers
    for(int j=tid; j<CS*9*CO; j+=NTHR){
      int c  = j % CO;
      int rr = j / CO;                     // local_cin*9 + dd
      wl[j] = wt[(cs*9 + rr)*Cout + cog*CO + c];
    }
    __syncthreads();

    for(int lc=0; lc<CS; lc++){
      const float* xc = x + ((size_t)b*Cin + cs + lc)*HW*HW;
      float xmv[PX+2], x0v[PX+2], xpv[PX+2];
      #pragma unroll
      for(int r=0;r<PX+2;r++){
        int hh = h0 - 1 + r;
        bool hv = (hh>=0) && (hh<HW);
        const float* xr = xc + hh*HW;
        x0v[r] =  hv            ? xr[w]   : 0.f;
        xmv[r] = (hv && w>0)    ? xr[w-1] : 0.f;
        xpv[r] = (hv && w<HW-1) ? xr[w+1] : 0.f;
      }
      const float4* w4 = (const float4*)(wl + lc*9*CO);
      #pragma unroll
      for(int dh=0;dh<3;dh++){
        float4 wa[NH4], wb[NH4], wc[NH4];
        #pragma unroll
        for(int g=0;g<NH4;g++){
          wa[g] = w4[(dh*3+0)*NH4+g];
          wb[g] = w4[(dh*3+1)*NH4+g];
          wc[g] = w4[(dh*3+2)*NH4+g];
        }
        #pragma unroll
        for(int g=0;g<NH4;g++){
          const float* A  = (const float*)&wa[g];
          const float* Bp = (const float*)&wb[g];
          const float* Cp = (const float*)&wc[g];
          #pragma unroll
          for(int cc=0;cc<4;cc++){
            #pragma unroll
            for(int px=0;px<PX;px++){
              int r = dh+px;
              accs[px][g*4+cc] += A[cc]*xmv[r] + Bp[cc]*x0v[r] + Cp[cc]*xpv[r];
            }
          }
        }
      }
    }
  }

  int co0 = cog*CO;
  size_t cbase = ((size_t)b*Cout + co0)*HW*HW;
  #pragma unroll
  for(int co=0; co<CO; co++){
    float bsv = bias[co0+co];
    if constexpr(!POOL){
      #pragma unroll
      for(int px=0; px<PX; px++){
        size_t idx = cbase + (size_t)co*HW*HW + (size_t)(h0+px)*HW + w;
        float mem = dm[idx] + accs[px][co] + bsv;
        out[idx] = mem > 0.f ? mem : 0.f;
        dm[idx]  = (mem > 0.5f) ? 0.f : 0.3f*mem;
      }
    } else if constexpr(PX==2){
      float vs = 0.f;
      #pragma unroll
      for(int px=0; px<2; px++){
        size_t idx = cbase + (size_t)co*HW*HW + (size_t)(h0+px)*HW + w;
        float mem = dm[idx] + accs[px][co] + bsv;
        float o = mem > 0.f ? mem : 0.f;
        dm[idx] = (mem > 0.5f) ? 0.f : 0.3f*mem;
        vs += o;
      }
      float s = vs + __shfl_xor(vs, 1, 64);
      if((w&1)==0){
        int ph = h0>>1, pw = w>>1;
        size_t pidx = ((size_t)b*Cout + co0+co)*(HW/2)*(HW/2) + (size_t)ph*(HW/2) + pw;
        float pm = dmp[pidx] + s*0.25f;
        outp[pidx] = pm > 0.f ? pm : 0.f;
        dmp[pidx]  = (pm > 0.5f) ? 0.f : 0.3f*pm;
      }
    } else { // PX==1, HW=16: pool (h,h^1) via lane^16, (w,w^1) via lane^1
      size_t idx = cbase + (size_t)co*HW*HW + (size_t)h0*HW + w;
      float mem = dm[idx] + accs[0][co] + bsv;
      float o = mem > 0.f ? mem : 0.f;
      dm[idx] = (mem > 0.5f) ? 0.f : 0.3f*mem;
      float s = o;
      s += __shfl_xor(s, 16, 64);
      s += __shfl_xor(s, 1, 64);
      if(((ty&1)==0) && ((w&1)==0)){
        int ph = h0>>1, pw = w>>1;
        size_t pidx = ((size_t)b*Cout + co0+co)*(HW/2)*(HW/2) + (size_t)ph*(HW/2) + pw;
        float pm = dmp[pidx] + s*0.25f;
        outp[pidx] = pm > 0.f ? pm : 0.f;
        dmp[pidx]  = (pm > 0.5f) ? 0.f : 0.3f*pm;
      }
    }
  }
}

// ---- FC1 partial tile: tile=(ks 0..31, ot 0..7); 256k x 32o; 128 slices ----
__device__ __forceinline__
void fc1_tile(int tile, int tid, const float* __restrict__ X,
              const float* __restrict__ Wf, float* __restrict__ u1s,
              float* __restrict__ lds)
{
  float* Wl = lds;          // 32*68
  float* Xl = lds + 32*68;  // 40*68
  int ot = tile & 7, ks = tile >> 3;
  int o0 = ot*32, k0 = ks*256;
  int w_id = tid >> 6, lane = tid & 63;
  int o_l = lane & 7, bg = lane >> 3;
  float acc[4][5];
  #pragma unroll
  for(int i=0;i<4;i++)
    #pragma unroll
    for(int j=0;j<5;j++) acc[i][j]=0.f;

  for(int c=0; c<4; c++){
    int kb = k0 + c*64;
    __syncthreads();
    for(int idx=tid; idx<512; idx+=NTHR){
      int r = idx >> 4, j = idx & 15;
      *(float4*)&Wl[r*68 + j*4] = *(const float4*)&Wf[(size_t)(o0+r)*8192 + kb + j*4];
    }
    for(int idx=tid; idx<640; idx+=NTHR){
      int r = idx >> 4, j = idx & 15;
      float4 v = make_float4(0.f,0.f,0.f,0.f);
      if(r < NB) v = *(const float4*)&X[(size_t)r*8192 + kb + j*4];
      *(float4*)&Xl[r*68 + j*4] = v;
    }
    __syncthreads();
    #pragma unroll
    for(int c4=0; c4<4; c4++){
      int g = w_id*4 + c4;
      float4 wv[4], xv[5];
      #pragma unroll
      for(int oi=0;oi<4;oi++) wv[oi] = *(const float4*)&Wl[(o_l+8*oi)*68 + g*4];
      #pragma unroll
      for(int bi=0;bi<5;bi++) xv[bi] = *(const float4*)&Xl[(bg*5+bi)*68 + g*4];
      #pragma unroll
      for(int oi=0;oi<4;oi++)
        #pragma unroll
        for(int bi=0;bi<5;bi++)
          acc[oi][bi] += wv[oi].x*xv[bi].x + wv[oi].y*xv[bi].y
                       + wv[oi].z*xv[bi].z + wv[oi].w*xv[bi].w;
    }
  }
  int slice = ks*4 + w_id;   // 0..127
  #pragma unroll
  for(int bi=0;bi<5;bi++){
    int b = bg*5 + bi;
    if(b < NB){
      #pragma unroll
      for(int oi=0;oi<4;oi++)
        u1s[((size_t)slice*NB + b)*256 + o0 + o_l + 8*oi] = acc[oi][bi];
    }
  }
}

// ---- FC1-reduce + LIAF + FC2 + LIAF + accumulate for batch b (lanes 0..63) ----
__device__ __forceinline__
void fc2_b(int b, int lane, const float* __restrict__ u1s,
           const float* __restrict__ bf1, const float* __restrict__ Wf2,
           const float* __restrict__ bf2, float* __restrict__ dmh1,
           float* __restrict__ dmh2, float* __restrict__ acc)
{
  float xv[4];
  #pragma unroll
  for(int j=0;j<4;j++){
    int o = lane + 64*j;
    float u = bf1[o];
    const float* p = u1s + (size_t)b*256 + o;
    for(int s=0;s<128;s++) u += p[(size_t)s*NB*256];
    int idx = b*256 + o;
    float mem = dmh1[idx] + u;
    xv[j] = mem > 0.f ? mem : 0.f;
    dmh1[idx] = (mem > 0.5f) ? 0.f : 0.3f*mem;
  }
  for(int o=0;o<11;o++){
    const float* wr = Wf2 + o*256;
    float s = xv[0]*wr[lane] + xv[1]*wr[lane+64] + xv[2]*wr[lane+128] + xv[3]*wr[lane+192];
    #pragma unroll
    for(int off=32; off>0; off>>=1) s += __shfl_down(s, off, 64);
    if(lane==0){
      int idx = b*11 + o;
      float mem = dmh2[idx] + s + bf2[o];
      float outv = mem > 0.f ? mem : 0.f;
      dmh2[idx] = (mem > 0.5f) ? 0.f : 0.3f*mem;
      acc[idx] += outv * (1.0f/60.0f);
    }
  }
}

// ---- ticket grab (all 256 threads) ----
__device__ __forceinline__ int grab(unsigned int* c, int tid, unsigned int* st){
  __syncthreads();
  if(tid==0) *st = atomicAdd(c, 1u);
  __syncthreads();
  return (int)(*st);
}

// ==================== cooperative mega-kernel ====================
__global__ void __launch_bounds__(NTHR, 2)
mega(Params p)
{
  cg::grid_group g = cg::this_grid();
  int tid = threadIdx.x;
  int gt  = blockIdx.x*NTHR + tid;
  int STR = gridDim.x*NTHR;
  __shared__ __align__(16) float wl[WLSZ];
  __shared__ unsigned int s_t;

  if(gt < 512) p.tk[gt] = 0u;
  prep_all(p, gt, STR);
  g.sync();

  for(int t=0; t<NT; t++){
    const float* xt = p.xb + (size_t)t*NB*2*32*32;
    for(;;){
      int tile = grab(p.tk + t*5+0, tid, &s_t);
      if(tile >= 576) break;
      conv_tile<2,64,32,8,2,8,false,2>(tile, tid, xt, p.w0t, p.b0,
                                       p.dm0, p.out0, nullptr, nullptr, wl);
    }
    if(t > 0){
      for(;;){
        int b = grab(p.tk + (t-1)*5+4, tid, &s_t);
        if(b >= NB) break;
        if(tid < 64) fc2_b(b, tid, p.u1s, p.bf1, p.Wf2, p.bf2, p.dmh1, p.dmh2, p.acc);
      }
    }
    g.sync();
    for(;;){
      int tile = grab(p.tk + t*5+1, tid, &s_t);
      if(tile >= 1152) break;
      conv_tile<64,128,32,8,2,8,true,64>(tile, tid, p.out0, p.w1t, p.b1,
                                         p.dm1, nullptr, p.dmp1, p.outp1, wl);
    }
    g.sync();
    for(;;){
      int tile = grab(p.tk + t*5+2, tid, &s_t);
      if(tile >= 576) break;
      conv_tile<128,128,16,8,1,16,true,64>(tile, tid, p.outp1, p.w2t, p.b2,
                                           p.dm2, nullptr, p.dmp2, p.outp2, wl);
    }
    g.sync();
    for(;;){
      int tile = grab(p.tk + t*5+3, tid, &s_t);
      if(tile >= 256) break;
      fc1_tile(tile, tid, p.outp2, p.Wf1, p.u1s, wl);
    }
    g.sync();
  }
  for(;;){
    int b = grab(p.tk + (NT-1)*5+4, tid, &s_t);
    if(b >= NB) break;
    if(tid < 64) fc2_b(b, tid, p.u1s, p.bf1, p.Wf2, p.bf2, p.dmh1, p.dmh2, p.acc);
  }
}

// ==================== fallback wrappers (regular launches) ====================
__global__ void __launch_bounds__(NTHR) k_prep(Params p){
  prep_all(p, blockIdx.x*NTHR + threadIdx.x, gridDim.x*NTHR);
}

template<int Cin,int Cout,int HW,int CO,int PX,int TY,bool POOL,int CS>
__global__ void __launch_bounds__(NTHR)
k_conv_g(const float* __restrict__ x, const float* __restrict__ wt,
         const float* __restrict__ bias, float* __restrict__ dm,
         float* __restrict__ out, float* __restrict__ dmp, float* __restrict__ outp){
  __shared__ __align__(16) float wl[WLSZ];
  conv_tile<Cin,Cout,HW,CO,PX,TY,POOL,CS>(blockIdx.x, threadIdx.x, x, wt, bias,
                                          dm, out, dmp, outp, wl);
}

__global__ void __launch_bounds__(NTHR)
k_fc1_g(const float* __restrict__ X, const float* __restrict__ Wf, float* __restrict__ u1s){
  __shared__ __align__(16) float lds[WLSZ];
  fc1_tile(blockIdx.x, threadIdx.x, X, Wf, u1s, lds);
}

__global__ void __launch_bounds__(64)
k_fc2_g(const float* __restrict__ u1s, const float* __restrict__ bf1,
        const float* __restrict__ Wf2, const float* __restrict__ bf2,
        float* __restrict__ dmh1, float* __restrict__ dmh2, float* __restrict__ acc){
  fc2_b(blockIdx.x, threadIdx.x, u1s, bf1, Wf2, bf2, dmh1, dmh2, acc);
}

// ==================== launch ====================
extern "C" void kernel_launch(void* const* d_in, const int* in_sizes, int n_in,
                              void* d_out, int out_size, void* d_ws, size_t ws_size,
                              hipStream_t stream) {
  Params p;
  p.data = (const float*)d_in[0];
  p.W0  = (const float*)d_in[2];  p.b0  = (const float*)d_in[3];
  p.W1  = (const float*)d_in[4];  p.b1  = (const float*)d_in[5];
  p.W2  = (const float*)d_in[6];  p.b2  = (const float*)d_in[7];
  p.Wf1 = (const float*)d_in[8];  p.bf1 = (const float*)d_in[9];
  p.Wf2 = (const float*)d_in[10]; p.bf2 = (const float*)d_in[11];
  p.acc = (float*)d_out;

  p.tk = (unsigned int*)d_ws;
  float* ws = (float*)d_ws + 512;
  const size_t S_XB   = (size_t)NT*NB*2*32*32;
  const size_t S_W0T  = 2*9*64;
  const size_t S_W1T  = 64*9*128;
  const size_t S_W2T  = 128*9*128;
  const size_t S_OUT0 = (size_t)NB*64*32*32;
  const size_t S_DM1  = (size_t)NB*128*32*32;
  const size_t S_OP1  = (size_t)NB*128*16*16;
  const size_t S_OP2  = (size_t)NB*128*8*8;
  const size_t S_OH1  = (size_t)NB*256;
  const size_t S_U1S  = (size_t)128*NB*256;

  p.xb    = ws;  ws += S_XB;
  p.w0t   = ws;  ws += S_W0T;
  p.w1t   = ws;  ws += S_W1T;
  p.w2t   = ws;  ws += S_W2T;
  p.out0  = ws;  ws += S_OUT0;
  p.outp1 = ws;  ws += S_OP1;
  p.outp2 = ws;  ws += S_OP2;
  p.u1s   = ws;  ws += S_U1S;
  p.dm0   = ws;  ws += S_OUT0;
  p.dm1   = ws;  ws += S_DM1;
  p.dmp1  = ws;  ws += S_OP1;
  p.dm2   = ws;  ws += S_OP1;
  p.dmp2  = ws;  ws += S_OP2;
  p.dmh1  = ws;  ws += S_OH1;
  p.dmh2  = ws;  ws += (size_t)NB*11;
  p.dmz   = p.dm0;
  p.dmz_n4 = (int)((S_OUT0 + S_DM1 + S_OP1 + S_OP1 + S_OP2 + S_OH1 + (size_t)NB*11) / 4);

  // ---- try cooperative path, grid sized by the runtime's own occupancy calc ----
  int maxB = 0;
  hipError_t oe = hipOccupancyMaxActiveBlocksPerMultiprocessor(&maxB, mega, NTHR, 0);
  bool done = false;
  if(oe == hipSuccess && maxB >= 1){
    int G = maxB * 256;
    if(G > 1024) G = 1024;
    void* args[] = { &p };
    hipError_t le = hipLaunchCooperativeKernel((const void*)mega, dim3(G), dim3(NTHR),
                                               args, 0, stream);
    done = (le == hipSuccess);
  }
  if(done) return;

  // ---- fallback: regular per-phase launches (known-good structure) ----
  k_prep<<<dim3(1024), dim3(NTHR), 0, stream>>>(p);
  for(int t=0; t<NT; t++){
    const float* xt = p.xb + (size_t)t*NB*2*32*32;
    k_conv_g<2,64,32,8,2,8,false,2><<<dim3(576), dim3(NTHR), 0, stream>>>(
        xt, p.w0t, p.b0, p.dm0, p.out0, nullptr, nullptr);
    k_conv_g<64,128,32,8,2,8,true,64><<<dim3(1152), dim3(NTHR), 0, stream>>>(
        p.out0, p.w1t, p.b1, p.dm1, nullptr, p.dmp1, p.outp1);
    k_conv_g<128,128,16,8,1,16,true,64><<<dim3(576), dim3(NTHR), 0, stream>>>(
        p.outp1, p.w2t, p.b2, p.dm2, nullptr, p.dmp2, p.outp2);
    k_fc1_g<<<dim3(256), dim3(NTHR), 0, stream>>>(p.outp2, p.Wf1, p.u1s);
    k_fc2_g<<<dim3(36), dim3(64), 0, stream>>>(p.u1s, p.bf1, p.Wf2, p.bf2,
                                               p.dmh1, p.dmh2, p.acc);
  }
}

// Round 6
// 14710.605 us; speedup vs baseline: 2.8915x; 2.8915x over previous
//
#include <hip/hip_runtime.h>

#define NB 36
#define NT 60
#define NTHR 256

struct Params {
  const float *data;
  const float *W0, *b0, *W1, *b1, *W2, *b2, *Wf1, *bf1, *Wf2, *bf2;
  float *xb, *w0t, *w1t, *w2t;
  float *out0, *outp1, *outp2, *u1s;
  float *dm0, *dm1, *dmp1, *dm2, *dmp2, *dmh1, *dmh2;
  float *acc;
  float *dmz; int dmz_n4;
};

// ---------------- prep: zero states/out, binarize+transpose input, transpose weights ----------------
__global__ void __launch_bounds__(NTHR) k_prep(Params p){
  int gt  = blockIdx.x*NTHR + threadIdx.x;
  int STR = gridDim.x*NTHR;
  if(gt < NB*11) p.acc[gt] = 0.f;
  for(int i=gt; i<p.dmz_n4; i+=STR) ((float4*)p.dmz)[i] = make_float4(0.f,0.f,0.f,0.f);
  for(int i=gt; i<NT*NB*2*32*32; i+=STR){
    int t = i / (NB*2*32*32);
    int r = i % (NB*2*32*32);
    p.xb[i] = (p.data[(size_t)r*NT + t] > 1.0f) ? 1.0f : 0.0f;
  }
  for(int i=gt; i<2*9*64; i+=STR){
    int co=i%64, rr=i/64; p.w0t[i] = p.W0[(co*2 + rr/9)*9 + rr%9];
  }
  for(int i=gt; i<64*9*128; i+=STR){
    int co=i%128, rr=i/128; p.w1t[i] = p.W1[(co*64 + rr/9)*9 + rr%9];
  }
  for(int i=gt; i<128*9*128; i+=STR){
    int co=i%128, rr=i/128; p.w2t[i] = p.W2[(co*128 + rr/9)*9 + rr%9];
  }
}

// ---------------- fused conv3x3 + LIAF (+ optional avgpool2 + LIAF) ----------------
// Thread: w = tid%HW, ty = tid/HW; PX rows x CO couts. Weights staged in LDS
// in CS-cin chunks; LDS reads are float4 broadcasts (conflict-free).
template<int Cin,int Cout,int HW,int CO,int PX,int TY,bool POOL,int CS>
__global__ void __launch_bounds__(HW*TY)
k_conv(const float* __restrict__ x, const float* __restrict__ wt,
       const float* __restrict__ bias, float* __restrict__ dm,
       float* __restrict__ out, float* __restrict__ dmp, float* __restrict__ outp)
{
  const int NCOG = Cout/CO;
  const int TH   = PX*TY;
  const int NHG  = HW/TH;
  const int NH4  = CO/4;
  const int NTHL = HW*TY;
  int tile = blockIdx.x;
  int tid  = threadIdx.x;
  int cog = tile % NCOG;
  int hg  = (tile/NCOG) % NHG;
  int b   = tile/(NCOG*NHG);
  int w   = tid % HW;
  int ty  = tid / HW;
  int h0  = hg*TH + ty*PX;

  __shared__ __align__(16) float wl[CS*9*CO];

  float accs[PX][CO];
  #pragma unroll
  for(int p=0;p<PX;p++)
    #pragma unroll
    for(int c=0;c<CO;c++) accs[p][c]=0.f;

  for(int cs=0; cs<Cin; cs+=CS){
    __syncthreads();
    for(int j=tid; j<CS*9*CO; j+=NTHL){
      int c  = j % CO;
      int rr = j / CO;
      wl[j] = wt[(cs*9 + rr)*Cout + cog*CO + c];
    }
    __syncthreads();

    for(int lc=0; lc<CS; lc++){
      const float* xc = x + ((size_t)b*Cin + cs + lc)*HW*HW;
      float xmv[PX+2], x0v[PX+2], xpv[PX+2];
      #pragma unroll
      for(int r=0;r<PX+2;r++){
        int hh = h0 - 1 + r;
        bool hv = (hh>=0) && (hh<HW);
        const float* xr = xc + hh*HW;
        x0v[r] =  hv            ? xr[w]   : 0.f;
        xmv[r] = (hv && w>0)    ? xr[w-1] : 0.f;
        xpv[r] = (hv && w<HW-1) ? xr[w+1] : 0.f;
      }
      const float4* w4 = (const float4*)(wl + lc*9*CO);
      #pragma unroll
      for(int dh=0;dh<3;dh++){
        float4 wa[NH4], wb[NH4], wc[NH4];
        #pragma unroll
        for(int g=0;g<NH4;g++){
          wa[g] = w4[(dh*3+0)*NH4+g];
          wb[g] = w4[(dh*3+1)*NH4+g];
          wc[g] = w4[(dh*3+2)*NH4+g];
        }
        #pragma unroll
        for(int g=0;g<NH4;g++){
          const float* A  = (const float*)&wa[g];
          const float* Bp = (const float*)&wb[g];
          const float* Cp = (const float*)&wc[g];
          #pragma unroll
          for(int cc=0;cc<4;cc++){
            #pragma unroll
            for(int px=0;px<PX;px++){
              int r = dh+px;
              accs[px][g*4+cc] += A[cc]*xmv[r] + Bp[cc]*x0v[r] + Cp[cc]*xpv[r];
            }
          }
        }
      }
    }
  }

  int co0 = cog*CO;
  size_t cbase = ((size_t)b*Cout + co0)*HW*HW;
  #pragma unroll
  for(int co=0; co<CO; co++){
    float bsv = bias[co0+co];
    if constexpr(!POOL){
      #pragma unroll
      for(int px=0; px<PX; px++){
        size_t idx = cbase + (size_t)co*HW*HW + (size_t)(h0+px)*HW + w;
        float mem = dm[idx] + accs[px][co] + bsv;
        out[idx] = mem > 0.f ? mem : 0.f;
        dm[idx]  = (mem > 0.5f) ? 0.f : 0.3f*mem;
      }
    } else if constexpr(PX==2){
      float vs = 0.f;
      #pragma unroll
      for(int px=0; px<2; px++){
        size_t idx = cbase + (size_t)co*HW*HW + (size_t)(h0+px)*HW + w;
        float mem = dm[idx] + accs[px][co] + bsv;
        float o = mem > 0.f ? mem : 0.f;
        dm[idx] = (mem > 0.5f) ? 0.f : 0.3f*mem;
        vs += o;
      }
      float s = vs + __shfl_xor(vs, 1, 64);
      if((w&1)==0){
        int ph = h0>>1, pw = w>>1;
        size_t pidx = ((size_t)b*Cout + co0+co)*(HW/2)*(HW/2) + (size_t)ph*(HW/2) + pw;
        float pm = dmp[pidx] + s*0.25f;
        outp[pidx] = pm > 0.f ? pm : 0.f;
        dmp[pidx]  = (pm > 0.5f) ? 0.f : 0.3f*pm;
      }
    } else { // PX==1, HW=16: pool (h,h^1) via lane^16, (w,w^1) via lane^1
      size_t idx = cbase + (size_t)co*HW*HW + (size_t)h0*HW + w;
      float mem = dm[idx] + accs[0][co] + bsv;
      float o = mem > 0.f ? mem : 0.f;
      dm[idx] = (mem > 0.5f) ? 0.f : 0.3f*mem;
      float s = o;
      s += __shfl_xor(s, 16, 64);
      s += __shfl_xor(s, 1, 64);
      if(((ty&1)==0) && ((w&1)==0)){
        int ph = h0>>1, pw = w>>1;
        size_t pidx = ((size_t)b*Cout + co0+co)*(HW/2)*(HW/2) + (size_t)ph*(HW/2) + pw;
        float pm = dmp[pidx] + s*0.25f;
        outp[pidx] = pm > 0.f ? pm : 0.f;
        dmp[pidx]  = (pm > 0.5f) ? 0.f : 0.3f*pm;
      }
    }
  }
}

// ---------------- FC1 partial GEMM -> 32 slices ----------------
// block = (ks 0..31, ot 0..7), 256 thr. 4 waves cover the 256-k span
// (interleaved float4 groups), then LDS-reduce across waves; wave0 writes
// slice ks for its 32-o range. u1s: [32][NB][256].
__global__ void __launch_bounds__(NTHR)
k_fc1(const float* __restrict__ X, const float* __restrict__ Wf,
      float* __restrict__ u1s){
  __shared__ __align__(16) float lds[4896];   // Wl 32*68 | Xl 40*68 ; reused for reduce
  float* Wl = lds;
  float* Xl = lds + 32*68;
  const int tid = threadIdx.x;
  int ot = blockIdx.x & 7, ks = blockIdx.x >> 3;
  int o0 = ot*32, k0 = ks*256;
  int w_id = tid >> 6, lane = tid & 63;
  int o_l = lane & 7, bg = lane >> 3;
  float acc[4][5];
  #pragma unroll
  for(int i=0;i<4;i++)
    #pragma unroll
    for(int j=0;j<5;j++) acc[i][j]=0.f;

  for(int c=0; c<4; c++){
    int kb = k0 + c*64;
    __syncthreads();
    for(int idx=tid; idx<512; idx+=NTHR){
      int r = idx >> 4, j = idx & 15;
      *(float4*)&Wl[r*68 + j*4] = *(const float4*)&Wf[(size_t)(o0+r)*8192 + kb + j*4];
    }
    for(int idx=tid; idx<640; idx+=NTHR){
      int r = idx >> 4, j = idx & 15;
      float4 v = make_float4(0.f,0.f,0.f,0.f);
      if(r < NB) v = *(const float4*)&X[(size_t)r*8192 + kb + j*4];
      *(float4*)&Xl[r*68 + j*4] = v;
    }
    __syncthreads();
    #pragma unroll
    for(int c4=0; c4<4; c4++){
      int g = w_id*4 + c4;
      float4 wv[4], xv[5];
      #pragma unroll
      for(int oi=0;oi<4;oi++) wv[oi] = *(const float4*)&Wl[(o_l+8*oi)*68 + g*4];
      #pragma unroll
      for(int bi=0;bi<5;bi++) xv[bi] = *(const float4*)&Xl[(bg*5+bi)*68 + g*4];
      #pragma unroll
      for(int oi=0;oi<4;oi++)
        #pragma unroll
        for(int bi=0;bi<5;bi++)
          acc[oi][bi] += wv[oi].x*xv[bi].x + wv[oi].y*xv[bi].y
                       + wv[oi].z*xv[bi].z + wv[oi].w*xv[bi].w;
    }
  }
  // cross-wave reduce: waves 1..3 dump, wave0 sums and writes slice ks
  __syncthreads();
  if(w_id > 0){
    float* r = lds + ((w_id-1)*64 + lane)*20;
    #pragma unroll
    for(int oi=0;oi<4;oi++)
      #pragma unroll
      for(int bi=0;bi<5;bi++) r[oi*5+bi] = acc[oi][bi];
  }
  __syncthreads();
  if(w_id == 0){
    #pragma unroll
    for(int wv=0;wv<3;wv++){
      float* r = lds + (wv*64 + lane)*20;
      #pragma unroll
      for(int oi=0;oi<4;oi++)
        #pragma unroll
        for(int bi=0;bi<5;bi++) acc[oi][bi] += r[oi*5+bi];
    }
    #pragma unroll
    for(int bi=0;bi<5;bi++){
      int b = bg*5 + bi;
      if(b < NB){
        #pragma unroll
        for(int oi=0;oi<4;oi++)
          u1s[((size_t)ks*NB + b)*256 + o0 + o_l + 8*oi] = acc[oi][bi];
      }
    }
  }
}

// ---------------- FC1-reduce + LIAF + FC2 + LIAF + accumulate ----------------
// 36 blocks x 256 thr. Thread o: sum 32 slices (coalesced), LIAF; then 4 waves
// split the 11 fc2 outputs.
__global__ void __launch_bounds__(NTHR)
k_fc2(const float* __restrict__ u1s, const float* __restrict__ bf1,
      const float* __restrict__ Wf2, const float* __restrict__ bf2,
      float* __restrict__ dmh1, float* __restrict__ dmh2, float* __restrict__ acc){
  __shared__ float xs[256];
  int b = blockIdx.x;
  int o = threadIdx.x;
  float u = bf1[o];
  const float* p = u1s + (size_t)b*256 + o;
  #pragma unroll
  for(int s=0;s<32;s++) u += p[(size_t)s*NB*256];
  int idx = b*256 + o;
  float mem = dmh1[idx] + u;
  float xo = mem > 0.f ? mem : 0.f;
  dmh1[idx] = (mem > 0.5f) ? 0.f : 0.3f*mem;
  xs[o] = xo;
  __syncthreads();
  int w_id = o >> 6, lane = o & 63;
  for(int oo=w_id; oo<11; oo+=4){
    const float* wr = Wf2 + oo*256;
    float s = xs[lane]*wr[lane] + xs[lane+64]*wr[lane+64]
            + xs[lane+128]*wr[lane+128] + xs[lane+192]*wr[lane+192];
    #pragma unroll
    for(int off=32; off>0; off>>=1) s += __shfl_down(s, off, 64);
    if(lane==0){
      int i2 = b*11 + oo;
      float m2 = dmh2[i2] + s + bf2[oo];
      float ov = m2 > 0.f ? m2 : 0.f;
      dmh2[i2] = (m2 > 0.5f) ? 0.f : 0.3f*m2;
      acc[i2] += ov * (1.0f/60.0f);
    }
  }
}

// ==================== launch ====================
extern "C" void kernel_launch(void* const* d_in, const int* in_sizes, int n_in,
                              void* d_out, int out_size, void* d_ws, size_t ws_size,
                              hipStream_t stream) {
  Params p;
  p.data = (const float*)d_in[0];
  p.W0  = (const float*)d_in[2];  p.b0  = (const float*)d_in[3];
  p.W1  = (const float*)d_in[4];  p.b1  = (const float*)d_in[5];
  p.W2  = (const float*)d_in[6];  p.b2  = (const float*)d_in[7];
  p.Wf1 = (const float*)d_in[8];  p.bf1 = (const float*)d_in[9];
  p.Wf2 = (const float*)d_in[10]; p.bf2 = (const float*)d_in[11];
  p.acc = (float*)d_out;

  float* ws = (float*)d_ws;
  const size_t S_XB   = (size_t)NT*NB*2*32*32;
  const size_t S_W0T  = 2*9*64;
  const size_t S_W1T  = 64*9*128;
  const size_t S_W2T  = 128*9*128;
  const size_t S_OUT0 = (size_t)NB*64*32*32;
  const size_t S_DM1  = (size_t)NB*128*32*32;
  const size_t S_OP1  = (size_t)NB*128*16*16;
  const size_t S_OP2  = (size_t)NB*128*8*8;
  const size_t S_OH1  = (size_t)NB*256;
  const size_t S_U1S  = (size_t)32*NB*256;

  p.xb    = ws;  ws += S_XB;
  p.w0t   = ws;  ws += S_W0T;
  p.w1t   = ws;  ws += S_W1T;
  p.w2t   = ws;  ws += S_W2T;
  p.out0  = ws;  ws += S_OUT0;
  p.outp1 = ws;  ws += S_OP1;
  p.outp2 = ws;  ws += S_OP2;
  p.u1s   = ws;  ws += S_U1S;
  p.dm0   = ws;  ws += S_OUT0;
  p.dm1   = ws;  ws += S_DM1;
  p.dmp1  = ws;  ws += S_OP1;
  p.dm2   = ws;  ws += S_OP1;
  p.dmp2  = ws;  ws += S_OP2;
  p.dmh1  = ws;  ws += S_OH1;
  p.dmh2  = ws;  ws += (size_t)NB*11;
  p.dmz   = p.dm0;
  p.dmz_n4 = (int)((S_OUT0 + S_DM1 + S_OP1 + S_OP1 + S_OP2 + S_OH1 + (size_t)NB*11) / 4);

  k_prep<<<dim3(1024), dim3(NTHR), 0, stream>>>(p);
  for(int t=0; t<NT; t++){
    const float* xt = p.xb + (size_t)t*NB*2*32*32;
    // conv0: 2->64 @32x32 (576 blocks)
    k_conv<2,64,32,8,2,8,false,2><<<dim3(576), dim3(NTHR), 0, stream>>>(
        xt, p.w0t, p.b0, p.dm0, p.out0, nullptr, nullptr);
    // conv1+pool1: 64->128 @32x32 (1152 blocks)
    k_conv<64,128,32,8,2,8,true,64><<<dim3(1152), dim3(NTHR), 0, stream>>>(
        p.out0, p.w1t, p.b1, p.dm1, nullptr, p.dmp1, p.outp1);
    // conv2+pool2: 128->128 @16x16 (576 blocks)
    k_conv<128,128,16,8,1,16,true,64><<<dim3(576), dim3(NTHR), 0, stream>>>(
        p.outp1, p.w2t, p.b2, p.dm2, nullptr, p.dmp2, p.outp2);
    // fc1 -> 32 slices (256 blocks)
    k_fc1<<<dim3(256), dim3(NTHR), 0, stream>>>(p.outp2, p.Wf1, p.u1s);
    // fc1-reduce + LIAF + fc2 + LIAF + accumulate (36 blocks)
    k_fc2<<<dim3(36), dim3(NTHR), 0, stream>>>(p.u1s, p.bf1, p.Wf2, p.bf2,
                                               p.dmh1, p.dmh2, p.acc);
  }
}